// Round 4
// baseline (145.920 us; speedup 1.0000x reference)
//
#include <hip/hip_runtime.h>
#include <math.h>

#define BB 8
#define TT 2048
#define NE 1024
#define HH 64
#define BT (BB * TT)

typedef __attribute__((ext_vector_type(8))) short s8v;   // 8 x bf16 fragment
typedef __attribute__((ext_vector_type(4))) float f4v;   // 4 x f32 accum
typedef __attribute__((ext_vector_type(4))) float f4raw; // raw vector for nt loads

__device__ inline unsigned short f2bf(float f) {
  union { float f; unsigned u; } v;
  v.f = f;
  unsigned r = (v.u + 0x7FFFu + ((v.u >> 16) & 1u)) >> 16;  // RNE
  return (unsigned short)r;
}

__device__ inline unsigned short f2bf_trunc(float f) {
  union { float f; unsigned u; } v;
  v.f = f;
  return (unsigned short)(v.u >> 16);
}

// ---------------------------------------------------------------------------
// Kernel 0: W [1024][64] f32 x3  ->  WT [192][1024] bf16 (rows: Q cols 0-63,
// K cols 64-127, V cols 128-191)
// ---------------------------------------------------------------------------
__global__ __launch_bounds__(256) void conv_wt_kernel(
    const float* __restrict__ Wq, const float* __restrict__ Wk,
    const float* __restrict__ Wv, unsigned short* __restrict__ WT) {
  const int idx = blockIdx.x * 256 + threadIdx.x;  // 0..3*65536-1
  const int m = idx >> 16;
  const int e = idx & 65535;
  const int n = e >> 6;
  const int h = e & 63;
  const float* W = (m == 0) ? Wq : (m == 1) ? Wk : Wv;
  WT[(size_t)m * 65536 + (size_t)h * NE + n] = f2bf(W[e]);
}

// ---------------------------------------------------------------------------
// Kernel 1: QKV projection, no-LDS MFMA.  1024 blocks x 256 thr (4 waves).
//   block -> row-tile (bid>>2)*64 (4 waves = 4 x 16-row groups, SAME 48 cols
//   = (bid&3)*48).  Waves share B columns: a barrier every 4 k-steps keeps
//   them k-synced so the 12 KB B-chunk stays L1-resident; x reads are
//   nontemporal (streaming) so they don't evict B from L1.
//   4 blocks/CU -> 16 waves/CU for latency hiding.
// ---------------------------------------------------------------------------
__global__ __launch_bounds__(256, 4) void qkv_proj_mfma(
    const float* __restrict__ x, const unsigned short* __restrict__ WT,
    unsigned short* __restrict__ Q, unsigned short* __restrict__ K,
    unsigned short* __restrict__ VT) {
  const int tid = threadIdx.x;
  const int lane = tid & 63;
  const int w = tid >> 6;
  const int lr = lane & 15, lg = lane >> 4;
  const int row0 = (blockIdx.x >> 2) * 64 + w * 16;
  const int colbase = (blockIdx.x & 3) * 48;

  f4v acc[3];
#pragma unroll
  for (int c = 0; c < 3; ++c) acc[c] = (f4v)0.f;

  const float* __restrict__ xr = x + (size_t)(row0 + lr) * NE + lg * 8;
  const unsigned short* bp0 = WT + (size_t)(colbase + 0 * 16 + lr) * NE + lg * 8;
  const unsigned short* bp1 = WT + (size_t)(colbase + 1 * 16 + lr) * NE + lg * 8;
  const unsigned short* bp2 = WT + (size_t)(colbase + 2 * 16 + lr) * NE + lg * 8;

#pragma unroll 4
  for (int ks = 0; ks < NE; ks += 32) {
    const f4raw a0 =
        __builtin_nontemporal_load(reinterpret_cast<const f4raw*>(xr + ks));
    const f4raw a1 =
        __builtin_nontemporal_load(reinterpret_cast<const f4raw*>(xr + ks) + 1);
    s8v a;
    a[0] = f2bf(a0[0]); a[1] = f2bf(a0[1]); a[2] = f2bf(a0[2]); a[3] = f2bf(a0[3]);
    a[4] = f2bf(a1[0]); a[5] = f2bf(a1[1]); a[6] = f2bf(a1[2]); a[7] = f2bf(a1[3]);
    const s8v b0 = *reinterpret_cast<const s8v*>(bp0 + ks);
    const s8v b1 = *reinterpret_cast<const s8v*>(bp1 + ks);
    const s8v b2 = *reinterpret_cast<const s8v*>(bp2 + ks);
    acc[0] = __builtin_amdgcn_mfma_f32_16x16x32_bf16(a, b0, acc[0], 0, 0, 0);
    acc[1] = __builtin_amdgcn_mfma_f32_16x16x32_bf16(a, b1, acc[1], 0, 0, 0);
    acc[2] = __builtin_amdgcn_mfma_f32_16x16x32_bf16(a, b2, acc[2], 0, 0, 0);
    if ((ks & 127) == 96) __syncthreads();  // keep waves k-synced for L1 B-reuse
  }

#pragma unroll
  for (int c = 0; c < 3; ++c) {
    const int col = colbase + c * 16 + lr;
    const int m = col >> 6;   // uniform per (colgroup, c)
    const int h = col & 63;
#pragma unroll
    for (int r = 0; r < 4; ++r) {
      const int rr = row0 + lg * 4 + r;  // D: row=(lane>>4)*4+reg
      const unsigned short bv = f2bf(acc[c][r]);
      if (m == 0) {
        Q[(size_t)rr * HH + h] = bv;
      } else if (m == 1) {
        K[(size_t)rr * HH + h] = bv;
      } else {
        const int bb = rr >> 11, t = rr & (TT - 1);
        VT[((size_t)bb * HH + h) * TT + t] = bv;
      }
    }
  }
}

// ---------------------------------------------------------------------------
// Kernel 2: causal flash attention, in-block split-k.  1024 blocks x 4 waves.
//   block -> (batch b = bid&7 for XCD/L2 affinity, q-tile qt = bid>>3, 16 rows).
//   Each wave runs an independent online-softmax flash loop over its k-slice
//   (no barriers in loop); one barrier then LDS combine.
//   Softmax in log2 domain: scores scaled by 0.125*log2(e), exp2f = v_exp_f32.
// ---------------------------------------------------------------------------
__global__ __launch_bounds__(256, 4) void flash_attn_mfma(
    const unsigned short* __restrict__ Q, const unsigned short* __restrict__ K,
    const unsigned short* __restrict__ VT, float* __restrict__ out) {
  __shared__ unsigned short pl[4][16][72];
  __shared__ float ol[4][16][64];
  __shared__ float ml[4][16];
  __shared__ float ll[4][16];

  const int tid = threadIdx.x;
  const int lane = tid & 63;
  const int w = tid >> 6;
  const int lr = lane & 15;
  const int lg = lane >> 4;
  const int bid = blockIdx.x;
  const int b = bid & 7;
  const int qt = bid >> 3;          // 0..127
  const int q0 = qt * 16;
  const size_t rowbase = (size_t)b * TT;
  const float SCL = 0.18033688011112042f;  // 0.125 * log2(e)

  const int nt = (qt >> 2) + 1;     // k-tiles of 64 covering rows < q0+16
  const int base = nt >> 2, rem = nt & 3;
  const int t0 = w * base + (w < rem ? w : rem);
  const int cnt = base + (w < rem ? 1 : 0);

  const s8v qf0 = *reinterpret_cast<const s8v*>(
      Q + (rowbase + q0 + lr) * HH + lg * 8);
  const s8v qf1 = *reinterpret_cast<const s8v*>(
      Q + (rowbase + q0 + lr) * HH + 32 + lg * 8);

  f4v o[4];
#pragma unroll
  for (int n = 0; n < 4; ++n) o[n] = (f4v)0.f;
  float mrow[4], lrow[4];
#pragma unroll
  for (int r = 0; r < 4; ++r) { mrow[r] = -INFINITY; lrow[r] = 0.f; }

  for (int kt = t0; kt < t0 + cnt; ++kt) {
    const int k0 = kt * 64;
    f4v s[4];
#pragma unroll
    for (int nk = 0; nk < 4; ++nk) s[nk] = (f4v)0.f;
#pragma unroll
    for (int nk = 0; nk < 4; ++nk) {
      const unsigned short* kp = K + (rowbase + k0 + 16 * nk + lr) * HH + lg * 8;
      const s8v kf0 = *reinterpret_cast<const s8v*>(kp);
      const s8v kf1 = *reinterpret_cast<const s8v*>(kp + 32);
      s[nk] = __builtin_amdgcn_mfma_f32_16x16x32_bf16(qf0, kf0, s[nk], 0, 0, 0);
      s[nk] = __builtin_amdgcn_mfma_f32_16x16x32_bf16(qf1, kf1, s[nk], 0, 0, 0);
    }
    // hoist V loads: L2 latency hides under softmax
    s8v vfr[2][4];
#pragma unroll
    for (int kh = 0; kh < 2; ++kh)
#pragma unroll
      for (int n = 0; n < 4; ++n)
        vfr[kh][n] = *reinterpret_cast<const s8v*>(
            VT + ((size_t)b * HH + 16 * n + lr) * TT + k0 + kh * 32 + lg * 8);

    const bool diag = (kt == nt - 1);
#pragma unroll
    for (int nk = 0; nk < 4; ++nk) {
#pragma unroll
      for (int r = 0; r < 4; ++r) {
        float v = s[nk][r] * SCL;   // log2-domain score
        if (diag) {
          const int kk = k0 + 16 * nk + lr;
          const int qq = q0 + lg * 4 + r;
          if (kk > qq) v = -INFINITY;
        }
        s[nk][r] = v;
      }
    }
    float scl[4];
#pragma unroll
    for (int r = 0; r < 4; ++r) {
      float mx = fmaxf(fmaxf(s[0][r], s[1][r]), fmaxf(s[2][r], s[3][r]));
#pragma unroll
      for (int off = 1; off < 16; off <<= 1)
        mx = fmaxf(mx, __shfl_xor(mx, off));
      const float mnew = fmaxf(mrow[r], mx);
      scl[r] = exp2f(mrow[r] - mnew);
      mrow[r] = mnew;
      float rs = 0.f;
#pragma unroll
      for (int nk = 0; nk < 4; ++nk) {
        const float p = exp2f(s[nk][r] - mnew);
        s[nk][r] = p;
        rs += p;
      }
#pragma unroll
      for (int off = 1; off < 16; off <<= 1)
        rs += __shfl_xor(rs, off);
      lrow[r] = lrow[r] * scl[r] + rs;
    }
#pragma unroll
    for (int n = 0; n < 4; ++n)
#pragma unroll
      for (int r = 0; r < 4; ++r) o[n][r] *= scl[r];
    // P: D-layout -> per-wave LDS (no barrier needed); truncation is enough
#pragma unroll
    for (int nk = 0; nk < 4; ++nk)
#pragma unroll
      for (int r = 0; r < 4; ++r)
        pl[w][lg * 4 + r][16 * nk + lr] = f2bf_trunc(s[nk][r]);
    // PV
#pragma unroll
    for (int kh = 0; kh < 2; ++kh) {
      const int pc = kh * 32 + lg * 8;
      const ushort4 plo = *reinterpret_cast<const ushort4*>(&pl[w][lr][pc]);
      const ushort4 phi = *reinterpret_cast<const ushort4*>(&pl[w][lr][pc + 4]);
      s8v pa;
      pa[0] = plo.x; pa[1] = plo.y; pa[2] = plo.z; pa[3] = plo.w;
      pa[4] = phi.x; pa[5] = phi.y; pa[6] = phi.z; pa[7] = phi.w;
#pragma unroll
      for (int n = 0; n < 4; ++n)
        o[n] = __builtin_amdgcn_mfma_f32_16x16x32_bf16(pa, vfr[kh][n], o[n], 0, 0, 0);
    }
  }

  // publish per-wave partials
#pragma unroll
  for (int n = 0; n < 4; ++n)
#pragma unroll
    for (int r = 0; r < 4; ++r) ol[w][lg * 4 + r][16 * n + lr] = o[n][r];
  if (lr == 0) {
#pragma unroll
    for (int r = 0; r < 4; ++r) {
      ml[w][lg * 4 + r] = mrow[r];
      ll[w][lg * 4 + r] = lrow[r];
    }
  }
  __syncthreads();

  // combine: thread -> (row = tid>>4, 4 cols at (tid&15)*4)
  const int row = tid >> 4;
  const int c0 = (tid & 15) * 4;
  float m0 = ml[0][row], m1 = ml[1][row], m2 = ml[2][row], m3 = ml[3][row];
  const float ms = fmaxf(fmaxf(m0, m1), fmaxf(m2, m3));
  const float w0 = exp2f(m0 - ms), w1 = exp2f(m1 - ms);
  const float w2 = exp2f(m2 - ms), w3 = exp2f(m3 - ms);
  const float lsum = w0 * ll[0][row] + w1 * ll[1][row] +
                     w2 * ll[2][row] + w3 * ll[3][row];
  float4 osum;
  osum.x = w0 * ol[0][row][c0 + 0] + w1 * ol[1][row][c0 + 0] +
           w2 * ol[2][row][c0 + 0] + w3 * ol[3][row][c0 + 0];
  osum.y = w0 * ol[0][row][c0 + 1] + w1 * ol[1][row][c0 + 1] +
           w2 * ol[2][row][c0 + 1] + w3 * ol[3][row][c0 + 1];
  osum.z = w0 * ol[0][row][c0 + 2] + w1 * ol[1][row][c0 + 2] +
           w2 * ol[2][row][c0 + 2] + w3 * ol[3][row][c0 + 2];
  osum.w = w0 * ol[0][row][c0 + 3] + w1 * ol[1][row][c0 + 3] +
           w2 * ol[2][row][c0 + 3] + w3 * ol[3][row][c0 + 3];
  const float inv = 1.0f / lsum;
  float4 res;
  res.x = osum.x * inv; res.y = osum.y * inv;
  res.z = osum.z * inv; res.w = osum.w * inv;
  *reinterpret_cast<float4*>(out + (rowbase + q0 + row) * HH + c0) = res;
}

extern "C" void kernel_launch(void* const* d_in, const int* in_sizes, int n_in,
                              void* d_out, int out_size, void* d_ws, size_t ws_size,
                              hipStream_t stream) {
  const float* x  = (const float*)d_in[0];
  const float* Wk = (const float*)d_in[1];
  const float* Wq = (const float*)d_in[2];
  const float* Wv = (const float*)d_in[3];
  float* out = (float*)d_out;

  unsigned short* ws = (unsigned short*)d_ws;
  unsigned short* Q  = ws;                           // BT*HH bf16
  unsigned short* K  = ws + (size_t)BT * HH;         // BT*HH bf16
  unsigned short* VT = ws + 2 * (size_t)BT * HH;     // B*HH*TT bf16
  unsigned short* WT = ws + 3 * (size_t)BT * HH;     // 192*1024 bf16

  conv_wt_kernel<<<768, 256, 0, stream>>>(Wq, Wk, Wv, WT);
  qkv_proj_mfma<<<1024, 256, 0, stream>>>(x, WT, Q, K, VT);
  flash_attn_mfma<<<1024, 256, 0, stream>>>(Q, K, VT, out);
}

// Round 6
// 126.542 us; speedup vs baseline: 1.1531x; 1.1531x over previous
//
#include <hip/hip_runtime.h>
#include <math.h>

#define BB 8
#define TT 2048
#define NE 1024
#define HH 64
#define BT (BB * TT)

typedef __attribute__((ext_vector_type(8))) short s8v;   // 8 x bf16 fragment
typedef __attribute__((ext_vector_type(4))) float f4v;   // 4 x f32 accum

__device__ inline unsigned short f2bf(float f) {
  union { float f; unsigned u; } v;
  v.f = f;
  unsigned r = (v.u + 0x7FFFu + ((v.u >> 16) & 1u)) >> 16;  // RNE
  return (unsigned short)r;
}

__device__ inline unsigned short f2bf_trunc(float f) {
  union { float f; unsigned u; } v;
  v.f = f;
  return (unsigned short)(v.u >> 16);
}

// packed f32x2 -> bf16x2 (RNE), src0 -> low16, src1 -> high16
__device__ inline unsigned cvtpk(float lo, float hi) {
  unsigned r;
  asm("v_cvt_pk_bf16_f32 %0, %1, %2" : "=v"(r) : "v"(lo), "v"(hi));
  return r;
}

// ---------------------------------------------------------------------------
// Kernel 0: W [1024][64] f32 x3  ->  WT [192][1024] bf16 (rows: Q cols 0-63,
// K cols 64-127, V cols 128-191)
// ---------------------------------------------------------------------------
__global__ __launch_bounds__(256) void conv_wt_kernel(
    const float* __restrict__ Wq, const float* __restrict__ Wk,
    const float* __restrict__ Wv, unsigned short* __restrict__ WT) {
  const int idx = blockIdx.x * 256 + threadIdx.x;  // 0..3*65536-1
  const int m = idx >> 16;
  const int e = idx & 65535;
  const int n = e >> 6;
  const int h = e & 63;
  const float* W = (m == 0) ? Wq : (m == 1) ? Wk : Wv;
  WT[(size_t)m * 65536 + (size_t)h * NE + n] = f2bf(W[e]);
}

// ---------------------------------------------------------------------------
// Kernel 1: QKV projection, no-LDS MFMA.  512 blocks x 512 thr (8 waves).
//   block owns 32 rows x ALL 192 cols -> x read EXACTLY ONCE from HBM.
//   wave w: row-group rg=w&1 (16 rows), col-group cg=w>>1 (48 cols, 3 frags).
//   B (WT, 384 KB) is L2-resident; x chunks L1-shared by the 4 col-groups.
//   2 blocks/CU -> 16 waves/CU; v_cvt_pk_bf16_f32 kills the f2bf VALU chain.
//   Grid MUST be BT/32 = 512 (r5 crash: 64-row geometry with 512 blocks OOB).
// ---------------------------------------------------------------------------
__global__ __launch_bounds__(512, 4) void qkv_proj_mfma(
    const float* __restrict__ x, const unsigned short* __restrict__ WT,
    unsigned short* __restrict__ Q, unsigned short* __restrict__ K,
    unsigned short* __restrict__ VT) {
  const int tid = threadIdx.x;
  const int lane = tid & 63;
  const int w = tid >> 6;
  const int rg = w & 1, cg = w >> 1;
  const int lr = lane & 15, lg = lane >> 4;
  const int row0 = blockIdx.x * 32 + rg * 16;
  const int colbase = cg * 48;

  f4v acc[3];
#pragma unroll
  for (int c = 0; c < 3; ++c) acc[c] = (f4v)0.f;

  const float* __restrict__ xr = x + (size_t)(row0 + lr) * NE + lg * 8;
  const unsigned short* bp0 = WT + (size_t)(colbase + 0 * 16 + lr) * NE + lg * 8;
  const unsigned short* bp1 = WT + (size_t)(colbase + 1 * 16 + lr) * NE + lg * 8;
  const unsigned short* bp2 = WT + (size_t)(colbase + 2 * 16 + lr) * NE + lg * 8;

#pragma unroll 4
  for (int ks = 0; ks < NE; ks += 32) {
    const float4 a0 = *reinterpret_cast<const float4*>(xr + ks);
    const float4 a1 = *reinterpret_cast<const float4*>(xr + ks + 4);
    union { unsigned u[4]; s8v v; } au;
    au.u[0] = cvtpk(a0.x, a0.y);
    au.u[1] = cvtpk(a0.z, a0.w);
    au.u[2] = cvtpk(a1.x, a1.y);
    au.u[3] = cvtpk(a1.z, a1.w);
    const s8v b0 = *reinterpret_cast<const s8v*>(bp0 + ks);
    const s8v b1 = *reinterpret_cast<const s8v*>(bp1 + ks);
    const s8v b2 = *reinterpret_cast<const s8v*>(bp2 + ks);
    acc[0] = __builtin_amdgcn_mfma_f32_16x16x32_bf16(au.v, b0, acc[0], 0, 0, 0);
    acc[1] = __builtin_amdgcn_mfma_f32_16x16x32_bf16(au.v, b1, acc[1], 0, 0, 0);
    acc[2] = __builtin_amdgcn_mfma_f32_16x16x32_bf16(au.v, b2, acc[2], 0, 0, 0);
  }

#pragma unroll
  for (int c = 0; c < 3; ++c) {
    const int col = colbase + c * 16 + lr;
    const int m = col >> 6;   // uniform per (cg, c): 16-col blocks don't cross 64
    const int h = col & 63;
#pragma unroll
    for (int r = 0; r < 4; ++r) {
      const int rr = row0 + lg * 4 + r;  // D: row=(lane>>4)*4+reg
      const unsigned short bv = f2bf(acc[c][r]);
      if (m == 0) {
        Q[(size_t)rr * HH + h] = bv;
      } else if (m == 1) {
        K[(size_t)rr * HH + h] = bv;
      } else {
        const int bb = rr >> 11, t = rr & (TT - 1);
        VT[((size_t)bb * HH + h) * TT + t] = bv;
      }
    }
  }
}

// ---------------------------------------------------------------------------
// Kernel 2: causal flash attention, in-block split-k.  1024 blocks x 4 waves.
//   block -> (batch b = bid&7 for XCD/L2 affinity, q-tile qt = bid>>3, 16 rows).
//   Each wave runs an independent online-softmax flash loop over its k-slice
//   (no barriers in loop); one barrier then LDS combine.
//   Softmax in log2 domain: scores scaled by 0.125*log2(e), exp2f = v_exp_f32.
// ---------------------------------------------------------------------------
__global__ __launch_bounds__(256, 4) void flash_attn_mfma(
    const unsigned short* __restrict__ Q, const unsigned short* __restrict__ K,
    const unsigned short* __restrict__ VT, float* __restrict__ out) {
  __shared__ unsigned short pl[4][16][72];
  __shared__ float ol[4][16][64];
  __shared__ float ml[4][16];
  __shared__ float ll[4][16];

  const int tid = threadIdx.x;
  const int lane = tid & 63;
  const int w = tid >> 6;
  const int lr = lane & 15;
  const int lg = lane >> 4;
  const int bid = blockIdx.x;
  const int b = bid & 7;
  const int qt = bid >> 3;          // 0..127
  const int q0 = qt * 16;
  const size_t rowbase = (size_t)b * TT;
  const float SCL = 0.18033688011112042f;  // 0.125 * log2(e)

  const int nt = (qt >> 2) + 1;     // k-tiles of 64 covering rows < q0+16
  const int base = nt >> 2, rem = nt & 3;
  const int t0 = w * base + (w < rem ? w : rem);
  const int cnt = base + (w < rem ? 1 : 0);

  const s8v qf0 = *reinterpret_cast<const s8v*>(
      Q + (rowbase + q0 + lr) * HH + lg * 8);
  const s8v qf1 = *reinterpret_cast<const s8v*>(
      Q + (rowbase + q0 + lr) * HH + 32 + lg * 8);

  f4v o[4];
#pragma unroll
  for (int n = 0; n < 4; ++n) o[n] = (f4v)0.f;
  float mrow[4], lrow[4];
#pragma unroll
  for (int r = 0; r < 4; ++r) { mrow[r] = -INFINITY; lrow[r] = 0.f; }

  for (int kt = t0; kt < t0 + cnt; ++kt) {
    const int k0 = kt * 64;
    f4v s[4];
#pragma unroll
    for (int nk = 0; nk < 4; ++nk) s[nk] = (f4v)0.f;
#pragma unroll
    for (int nk = 0; nk < 4; ++nk) {
      const unsigned short* kp = K + (rowbase + k0 + 16 * nk + lr) * HH + lg * 8;
      const s8v kf0 = *reinterpret_cast<const s8v*>(kp);
      const s8v kf1 = *reinterpret_cast<const s8v*>(kp + 32);
      s[nk] = __builtin_amdgcn_mfma_f32_16x16x32_bf16(qf0, kf0, s[nk], 0, 0, 0);
      s[nk] = __builtin_amdgcn_mfma_f32_16x16x32_bf16(qf1, kf1, s[nk], 0, 0, 0);
    }
    // hoist V loads: L2 latency hides under softmax
    s8v vfr[2][4];
#pragma unroll
    for (int kh = 0; kh < 2; ++kh)
#pragma unroll
      for (int n = 0; n < 4; ++n)
        vfr[kh][n] = *reinterpret_cast<const s8v*>(
            VT + ((size_t)b * HH + 16 * n + lr) * TT + k0 + kh * 32 + lg * 8);

    const bool diag = (kt == nt - 1);
#pragma unroll
    for (int nk = 0; nk < 4; ++nk) {
#pragma unroll
      for (int r = 0; r < 4; ++r) {
        float v = s[nk][r] * SCL;   // log2-domain score
        if (diag) {
          const int kk = k0 + 16 * nk + lr;
          const int qq = q0 + lg * 4 + r;
          if (kk > qq) v = -INFINITY;
        }
        s[nk][r] = v;
      }
    }
    float scl[4];
#pragma unroll
    for (int r = 0; r < 4; ++r) {
      float mx = fmaxf(fmaxf(s[0][r], s[1][r]), fmaxf(s[2][r], s[3][r]));
#pragma unroll
      for (int off = 1; off < 16; off <<= 1)
        mx = fmaxf(mx, __shfl_xor(mx, off));
      const float mnew = fmaxf(mrow[r], mx);
      scl[r] = exp2f(mrow[r] - mnew);
      mrow[r] = mnew;
      float rs = 0.f;
#pragma unroll
      for (int nk = 0; nk < 4; ++nk) {
        const float p = exp2f(s[nk][r] - mnew);
        s[nk][r] = p;
        rs += p;
      }
#pragma unroll
      for (int off = 1; off < 16; off <<= 1)
        rs += __shfl_xor(rs, off);
      lrow[r] = lrow[r] * scl[r] + rs;
    }
#pragma unroll
    for (int n = 0; n < 4; ++n)
#pragma unroll
      for (int r = 0; r < 4; ++r) o[n][r] *= scl[r];
    // P: D-layout -> per-wave LDS (no barrier needed); truncation is enough
#pragma unroll
    for (int nk = 0; nk < 4; ++nk)
#pragma unroll
      for (int r = 0; r < 4; ++r)
        pl[w][lg * 4 + r][16 * nk + lr] = f2bf_trunc(s[nk][r]);
    // PV
#pragma unroll
    for (int kh = 0; kh < 2; ++kh) {
      const int pc = kh * 32 + lg * 8;
      const ushort4 plo = *reinterpret_cast<const ushort4*>(&pl[w][lr][pc]);
      const ushort4 phi = *reinterpret_cast<const ushort4*>(&pl[w][lr][pc + 4]);
      s8v pa;
      pa[0] = plo.x; pa[1] = plo.y; pa[2] = plo.z; pa[3] = plo.w;
      pa[4] = phi.x; pa[5] = phi.y; pa[6] = phi.z; pa[7] = phi.w;
#pragma unroll
      for (int n = 0; n < 4; ++n)
        o[n] = __builtin_amdgcn_mfma_f32_16x16x32_bf16(pa, vfr[kh][n], o[n], 0, 0, 0);
    }
  }

  // publish per-wave partials
#pragma unroll
  for (int n = 0; n < 4; ++n)
#pragma unroll
    for (int r = 0; r < 4; ++r) ol[w][lg * 4 + r][16 * n + lr] = o[n][r];
  if (lr == 0) {
#pragma unroll
    for (int r = 0; r < 4; ++r) {
      ml[w][lg * 4 + r] = mrow[r];
      ll[w][lg * 4 + r] = lrow[r];
    }
  }
  __syncthreads();

  // combine: thread -> (row = tid>>4, 4 cols at (tid&15)*4)
  const int row = tid >> 4;
  const int c0 = (tid & 15) * 4;
  float m0 = ml[0][row], m1 = ml[1][row], m2 = ml[2][row], m3 = ml[3][row];
  const float ms = fmaxf(fmaxf(m0, m1), fmaxf(m2, m3));
  const float w0 = exp2f(m0 - ms), w1 = exp2f(m1 - ms);
  const float w2 = exp2f(m2 - ms), w3 = exp2f(m3 - ms);
  const float lsum = w0 * ll[0][row] + w1 * ll[1][row] +
                     w2 * ll[2][row] + w3 * ll[3][row];
  float4 osum;
  osum.x = w0 * ol[0][row][c0 + 0] + w1 * ol[1][row][c0 + 0] +
           w2 * ol[2][row][c0 + 0] + w3 * ol[3][row][c0 + 0];
  osum.y = w0 * ol[0][row][c0 + 1] + w1 * ol[1][row][c0 + 1] +
           w2 * ol[2][row][c0 + 1] + w3 * ol[3][row][c0 + 1];
  osum.z = w0 * ol[0][row][c0 + 2] + w1 * ol[1][row][c0 + 2] +
           w2 * ol[2][row][c0 + 2] + w3 * ol[3][row][c0 + 2];
  osum.w = w0 * ol[0][row][c0 + 3] + w1 * ol[1][row][c0 + 3] +
           w2 * ol[2][row][c0 + 3] + w3 * ol[3][row][c0 + 3];
  const float inv = 1.0f / lsum;
  float4 res;
  res.x = osum.x * inv; res.y = osum.y * inv;
  res.z = osum.z * inv; res.w = osum.w * inv;
  *reinterpret_cast<float4*>(out + (rowbase + q0 + row) * HH + c0) = res;
}

extern "C" void kernel_launch(void* const* d_in, const int* in_sizes, int n_in,
                              void* d_out, int out_size, void* d_ws, size_t ws_size,
                              hipStream_t stream) {
  const float* x  = (const float*)d_in[0];
  const float* Wk = (const float*)d_in[1];
  const float* Wq = (const float*)d_in[2];
  const float* Wv = (const float*)d_in[3];
  float* out = (float*)d_out;

  unsigned short* ws = (unsigned short*)d_ws;
  unsigned short* Q  = ws;                           // BT*HH bf16
  unsigned short* K  = ws + (size_t)BT * HH;         // BT*HH bf16
  unsigned short* VT = ws + 2 * (size_t)BT * HH;     // B*HH*TT bf16
  unsigned short* WT = ws + 3 * (size_t)BT * HH;     // 192*1024 bf16

  conv_wt_kernel<<<768, 256, 0, stream>>>(Wq, Wk, Wv, WT);
  qkv_proj_mfma<<<512, 512, 0, stream>>>(x, WT, Q, K, VT);
  flash_attn_mfma<<<1024, 256, 0, stream>>>(Q, K, VT, out);
}

// Round 7
// 77.369 us; speedup vs baseline: 1.8860x; 1.6356x over previous
//
#include <hip/hip_runtime.h>
#include <math.h>

#define BB 8
#define TT 2048
#define NE 1024
#define HH 64
#define BT (BB * TT)

typedef __attribute__((ext_vector_type(8))) short s8v;   // 8 x bf16 fragment
typedef __attribute__((ext_vector_type(4))) float f4v;   // 4 x f32 accum

__device__ inline unsigned short f2bf(float f) {
  union { float f; unsigned u; } v;
  v.f = f;
  unsigned r = (v.u + 0x7FFFu + ((v.u >> 16) & 1u)) >> 16;  // RNE
  return (unsigned short)r;
}

__device__ inline unsigned short f2bf_trunc(float f) {
  union { float f; unsigned u; } v;
  v.f = f;
  return (unsigned short)(v.u >> 16);
}

// packed f32x2 -> bf16x2 (RNE), src0 -> low16, src1 -> high16
__device__ inline unsigned cvtpk(float lo, float hi) {
  unsigned r;
  asm("v_cvt_pk_bf16_f32 %0, %1, %2" : "=v"(r) : "v"(lo), "v"(hi));
  return r;
}

// async global->LDS, 16B per lane; l must be the wave-uniform base
__device__ inline void glds16(const unsigned short* g, unsigned short* l) {
  __builtin_amdgcn_global_load_lds(
      (const __attribute__((address_space(1))) unsigned*)g,
      (__attribute__((address_space(3))) unsigned*)l, 16, 0, 0);
}

// ---------------------------------------------------------------------------
// Kernel 0: W [1024][64] f32 x3 -> WTswz [192][1024] bf16, XOR-swizzled:
//   storage 16B-unit c8 of row r holds logical unit (c8&~7)|((c8&7)^(r&7)).
//   (8-unit = 128B chunks match the qkv B-tile row; glds then copies linearly
//   and the ds_read applies the same XOR -> conflict-minimal, rule #21.)
// ---------------------------------------------------------------------------
__global__ __launch_bounds__(256) void conv_wt_kernel(
    const float* __restrict__ Wq, const float* __restrict__ Wk,
    const float* __restrict__ Wv, unsigned short* __restrict__ WTswz) {
  const int idx = blockIdx.x * 256 + threadIdx.x;  // 192*128 = 24576
  const int r = idx >> 7;          // output row 0..191
  const int c8 = idx & 127;        // storage 16B-unit
  const int l8 = (c8 & ~7) | ((c8 & 7) ^ (r & 7));
  const int n0 = l8 * 8;
  const int m = r >> 6, h = r & 63;
  const float* W = (m == 0) ? Wq : (m == 1) ? Wk : Wv;
  unsigned short v[8];
#pragma unroll
  for (int j = 0; j < 8; ++j) v[j] = f2bf(W[(size_t)(n0 + j) * HH + h]);
  *reinterpret_cast<uint4*>(WTswz + (size_t)r * NE + c8 * 8) =
      *reinterpret_cast<const uint4*>(v);
}

// ---------------------------------------------------------------------------
// Kernel 1: QKV projection, m97-style pipelined MFMA GEMM.
//   M=16384 N=192 K=1024; BM=32, BN=192, BK=64; 512 blocks (2/CU) x 4 waves.
//   wave w: rows (w&1)*16, cols (w>>1)*96 (6 frags).  Per K-tile:
//     A: x f32 -> regs -> cvt_pk -> ds_write_b128 into padded [32][72] bf16.
//     B: global_load_lds 16B linear from pre-swizzled WTswz into [192][64].
//   2-phase double-buffer, one __syncthreads per tile (T3 minimum recipe).
// ---------------------------------------------------------------------------
__global__ __launch_bounds__(256, 2) void qkv_proj_mfma(
    const float* __restrict__ x, const unsigned short* __restrict__ WTswz,
    unsigned short* __restrict__ Q, unsigned short* __restrict__ K,
    unsigned short* __restrict__ VT) {
  __shared__ __align__(16) unsigned short Abuf[2][32 * 72];   //  4.5 KB each
  __shared__ __align__(16) unsigned short Bbuf[2][192 * 64];  // 24   KB each

  const int tid = threadIdx.x;
  const int lane = tid & 63;
  const int w = tid >> 6;
  const int rg = w & 1, cg = w >> 1;
  const int lr = lane & 15, lg = lane >> 4;
  const int row0 = blockIdx.x * 32;

  // A staging geometry: lane -> (arow = tid>>3, aunit = tid&7)
  const int arow = tid >> 3, aunit = tid & 7;
  const float* __restrict__ xrow = x + (size_t)(row0 + arow) * NE + aunit * 8;
  unsigned short* const awr = &Abuf[0][0] + arow * 72 + aunit * 8;  // +buf*2304

  // B staging: wave w covers cols w*48..w*48+47; 6 glds of 8 cols each
  const int bcol = w * 48 + (lane >> 3);          // + j*8
  const unsigned short* const bsrc0 =
      WTswz + (size_t)bcol * NE + (lane & 7) * 8;  // + j*8*NE + kc
  unsigned short* const bdst0 = &Bbuf[0][0] + (w * 48) * 64;  // + j*512 + buf*12288

  f4v acc[6];
#pragma unroll
  for (int c = 0; c < 6; ++c) acc[c] = (f4v)0.f;

  // ---- prologue: stage tile 0 into buf 0
  float4 a0 = *reinterpret_cast<const float4*>(xrow);
  float4 a1 = *reinterpret_cast<const float4*>(xrow + 4);
#pragma unroll
  for (int j = 0; j < 6; ++j)
    glds16(bsrc0 + (size_t)j * 8 * NE, bdst0 + j * 512);
  {
    unsigned au[4] = {cvtpk(a0.x, a0.y), cvtpk(a0.z, a0.w),
                      cvtpk(a1.x, a1.y), cvtpk(a1.z, a1.w)};
    *reinterpret_cast<uint4*>(awr) = *reinterpret_cast<const uint4*>(au);
  }
  __syncthreads();

  int cur = 0;
  for (int t = 0; t < 16; ++t) {
    const int kcn = (t + 1) * 64;
    if (t < 15) {  // issue next tile's loads before compute (T14/T3)
      a0 = *reinterpret_cast<const float4*>(xrow + kcn);
      a1 = *reinterpret_cast<const float4*>(xrow + kcn + 4);
#pragma unroll
      for (int j = 0; j < 6; ++j)
        glds16(bsrc0 + (size_t)j * 8 * NE + kcn,
               bdst0 + (cur ^ 1) * 12288 + j * 512);
    }
    // ---- compute from buf[cur]
    const unsigned short* Ab = &Abuf[cur][0];
    const unsigned short* Bb = &Bbuf[cur][0];
#pragma unroll
    for (int ks = 0; ks < 2; ++ks) {  // k-slices of 32
      const s8v a = *reinterpret_cast<const s8v*>(
          Ab + (rg * 16 + lr) * 72 + ks * 32 + lg * 8);
#pragma unroll
      for (int c = 0; c < 6; ++c) {
        const int col = cg * 96 + c * 16 + lr;
        const int uraw = (lg + ks * 4) ^ (lr & 7);
        const s8v b = *reinterpret_cast<const s8v*>(Bb + col * 64 + uraw * 8);
        acc[c] = __builtin_amdgcn_mfma_f32_16x16x32_bf16(a, b, acc[c], 0, 0, 0);
      }
    }
    if (t < 15) {
      unsigned au[4] = {cvtpk(a0.x, a0.y), cvtpk(a0.z, a0.w),
                        cvtpk(a1.x, a1.y), cvtpk(a1.z, a1.w)};
      *reinterpret_cast<uint4*>(awr + (cur ^ 1) * 2304) =
          *reinterpret_cast<const uint4*>(au);
      __syncthreads();  // drains glds (vmcnt) + ds_write, then barrier
      cur ^= 1;
    }
  }

  // ---- epilogue
#pragma unroll
  for (int c = 0; c < 6; ++c) {
    const int col = cg * 96 + c * 16 + lr;
    const int m = col >> 6;  // uniform per (cg,c)
    const int h = col & 63;
#pragma unroll
    for (int r = 0; r < 4; ++r) {
      const int rr = row0 + rg * 16 + lg * 4 + r;  // D: row=(lane>>4)*4+reg
      const unsigned short bv = f2bf(acc[c][r]);
      if (m == 0) {
        Q[(size_t)rr * HH + h] = bv;
      } else if (m == 1) {
        K[(size_t)rr * HH + h] = bv;
      } else {
        const int bb = rr >> 11, tt2 = rr & (TT - 1);
        VT[((size_t)bb * HH + h) * TT + tt2] = bv;
      }
    }
  }
}

// ---------------------------------------------------------------------------
// Kernel 2: causal flash attention, in-block split-k.  1024 blocks x 4 waves.
//   (unchanged from round 6 — passing, next optimization target)
// ---------------------------------------------------------------------------
__global__ __launch_bounds__(256, 4) void flash_attn_mfma(
    const unsigned short* __restrict__ Q, const unsigned short* __restrict__ K,
    const unsigned short* __restrict__ VT, float* __restrict__ out) {
  __shared__ unsigned short pl[4][16][72];
  __shared__ float ol[4][16][64];
  __shared__ float ml[4][16];
  __shared__ float ll[4][16];

  const int tid = threadIdx.x;
  const int lane = tid & 63;
  const int w = tid >> 6;
  const int lr = lane & 15;
  const int lg = lane >> 4;
  const int bid = blockIdx.x;
  const int b = bid & 7;
  const int qt = bid >> 3;          // 0..127
  const int q0 = qt * 16;
  const size_t rowbase = (size_t)b * TT;
  const float SCL = 0.18033688011112042f;  // 0.125 * log2(e)

  const int nt = (qt >> 2) + 1;     // k-tiles of 64 covering rows < q0+16
  const int base = nt >> 2, rem = nt & 3;
  const int t0 = w * base + (w < rem ? w : rem);
  const int cnt = base + (w < rem ? 1 : 0);

  const s8v qf0 = *reinterpret_cast<const s8v*>(
      Q + (rowbase + q0 + lr) * HH + lg * 8);
  const s8v qf1 = *reinterpret_cast<const s8v*>(
      Q + (rowbase + q0 + lr) * HH + 32 + lg * 8);

  f4v o[4];
#pragma unroll
  for (int n = 0; n < 4; ++n) o[n] = (f4v)0.f;
  float mrow[4], lrow[4];
#pragma unroll
  for (int r = 0; r < 4; ++r) { mrow[r] = -INFINITY; lrow[r] = 0.f; }

  for (int kt = t0; kt < t0 + cnt; ++kt) {
    const int k0 = kt * 64;
    f4v s[4];
#pragma unroll
    for (int nk = 0; nk < 4; ++nk) s[nk] = (f4v)0.f;
#pragma unroll
    for (int nk = 0; nk < 4; ++nk) {
      const unsigned short* kp = K + (rowbase + k0 + 16 * nk + lr) * HH + lg * 8;
      const s8v kf0 = *reinterpret_cast<const s8v*>(kp);
      const s8v kf1 = *reinterpret_cast<const s8v*>(kp + 32);
      s[nk] = __builtin_amdgcn_mfma_f32_16x16x32_bf16(qf0, kf0, s[nk], 0, 0, 0);
      s[nk] = __builtin_amdgcn_mfma_f32_16x16x32_bf16(qf1, kf1, s[nk], 0, 0, 0);
    }
    // hoist V loads: L2 latency hides under softmax
    s8v vfr[2][4];
#pragma unroll
    for (int kh = 0; kh < 2; ++kh)
#pragma unroll
      for (int n = 0; n < 4; ++n)
        vfr[kh][n] = *reinterpret_cast<const s8v*>(
            VT + ((size_t)b * HH + 16 * n + lr) * TT + k0 + kh * 32 + lg * 8);

    const bool diag = (kt == nt - 1);
#pragma unroll
    for (int nk = 0; nk < 4; ++nk) {
#pragma unroll
      for (int r = 0; r < 4; ++r) {
        float v = s[nk][r] * SCL;   // log2-domain score
        if (diag) {
          const int kk = k0 + 16 * nk + lr;
          const int qq = q0 + lg * 4 + r;
          if (kk > qq) v = -INFINITY;
        }
        s[nk][r] = v;
      }
    }
    float scl[4];
#pragma unroll
    for (int r = 0; r < 4; ++r) {
      float mx = fmaxf(fmaxf(s[0][r], s[1][r]), fmaxf(s[2][r], s[3][r]));
#pragma unroll
      for (int off = 1; off < 16; off <<= 1)
        mx = fmaxf(mx, __shfl_xor(mx, off));
      const float mnew = fmaxf(mrow[r], mx);
      scl[r] = exp2f(mrow[r] - mnew);
      mrow[r] = mnew;
      float rs = 0.f;
#pragma unroll
      for (int nk = 0; nk < 4; ++nk) {
        const float p = exp2f(s[nk][r] - mnew);
        s[nk][r] = p;
        rs += p;
      }
#pragma unroll
      for (int off = 1; off < 16; off <<= 1)
        rs += __shfl_xor(rs, off);
      lrow[r] = lrow[r] * scl[r] + rs;
    }
#pragma unroll
    for (int n = 0; n < 4; ++n)
#pragma unroll
      for (int r = 0; r < 4; ++r) o[n][r] *= scl[r];
    // P: D-layout -> per-wave LDS (no barrier needed); truncation is enough
#pragma unroll
    for (int nk = 0; nk < 4; ++nk)
#pragma unroll
      for (int r = 0; r < 4; ++r)
        pl[w][lg * 4 + r][16 * nk + lr] = f2bf_trunc(s[nk][r]);
    // PV
#pragma unroll
    for (int kh = 0; kh < 2; ++kh) {
      const int pc = kh * 32 + lg * 8;
      const ushort4 plo = *reinterpret_cast<const ushort4*>(&pl[w][lr][pc]);
      const ushort4 phi = *reinterpret_cast<const ushort4*>(&pl[w][lr][pc + 4]);
      s8v pa;
      pa[0] = plo.x; pa[1] = plo.y; pa[2] = plo.z; pa[3] = plo.w;
      pa[4] = phi.x; pa[5] = phi.y; pa[6] = phi.z; pa[7] = phi.w;
#pragma unroll
      for (int n = 0; n < 4; ++n)
        o[n] = __builtin_amdgcn_mfma_f32_16x16x32_bf16(pa, vfr[kh][n], o[n], 0, 0, 0);
    }
  }

  // publish per-wave partials
#pragma unroll
  for (int n = 0; n < 4; ++n)
#pragma unroll
    for (int r = 0; r < 4; ++r) ol[w][lg * 4 + r][16 * n + lr] = o[n][r];
  if (lr == 0) {
#pragma unroll
    for (int r = 0; r < 4; ++r) {
      ml[w][lg * 4 + r] = mrow[r];
      ll[w][lg * 4 + r] = lrow[r];
    }
  }
  __syncthreads();

  // combine: thread -> (row = tid>>4, 4 cols at (tid&15)*4)
  const int row = tid >> 4;
  const int c0 = (tid & 15) * 4;
  float m0 = ml[0][row], m1 = ml[1][row], m2 = ml[2][row], m3 = ml[3][row];
  const float ms = fmaxf(fmaxf(m0, m1), fmaxf(m2, m3));
  const float w0 = exp2f(m0 - ms), w1 = exp2f(m1 - ms);
  const float w2 = exp2f(m2 - ms), w3 = exp2f(m3 - ms);
  const float lsum = w0 * ll[0][row] + w1 * ll[1][row] +
                     w2 * ll[2][row] + w3 * ll[3][row];
  float4 osum;
  osum.x = w0 * ol[0][row][c0 + 0] + w1 * ol[1][row][c0 + 0] +
           w2 * ol[2][row][c0 + 0] + w3 * ol[3][row][c0 + 0];
  osum.y = w0 * ol[0][row][c0 + 1] + w1 * ol[1][row][c0 + 1] +
           w2 * ol[2][row][c0 + 1] + w3 * ol[3][row][c0 + 1];
  osum.z = w0 * ol[0][row][c0 + 2] + w1 * ol[1][row][c0 + 2] +
           w2 * ol[2][row][c0 + 2] + w3 * ol[3][row][c0 + 2];
  osum.w = w0 * ol[0][row][c0 + 3] + w1 * ol[1][row][c0 + 3] +
           w2 * ol[2][row][c0 + 3] + w3 * ol[3][row][c0 + 3];
  const float inv = 1.0f / lsum;
  float4 res;
  res.x = osum.x * inv; res.y = osum.y * inv;
  res.z = osum.z * inv; res.w = osum.w * inv;
  *reinterpret_cast<float4*>(out + (rowbase + q0 + row) * HH + c0) = res;
}

extern "C" void kernel_launch(void* const* d_in, const int* in_sizes, int n_in,
                              void* d_out, int out_size, void* d_ws, size_t ws_size,
                              hipStream_t stream) {
  const float* x  = (const float*)d_in[0];
  const float* Wk = (const float*)d_in[1];
  const float* Wq = (const float*)d_in[2];
  const float* Wv = (const float*)d_in[3];
  float* out = (float*)d_out;

  unsigned short* ws = (unsigned short*)d_ws;
  unsigned short* Q  = ws;                           // BT*HH bf16
  unsigned short* K  = ws + (size_t)BT * HH;         // BT*HH bf16
  unsigned short* VT = ws + 2 * (size_t)BT * HH;     // B*HH*TT bf16
  unsigned short* WT = ws + 3 * (size_t)BT * HH;     // 192*1024 bf16 (swizzled)

  conv_wt_kernel<<<96, 256, 0, stream>>>(Wq, Wk, Wv, WT);
  qkv_proj_mfma<<<512, 256, 0, stream>>>(x, WT, Q, K, VT);
  flash_attn_mfma<<<1024, 256, 0, stream>>>(Q, K, VT, out);
}

// Round 8
// 72.997 us; speedup vs baseline: 1.9990x; 1.0599x over previous
//
#include <hip/hip_runtime.h>
#include <math.h>

#define BB 8
#define TT 2048
#define NE 1024
#define HH 64
#define BT (BB * TT)

typedef __attribute__((ext_vector_type(8))) short s8v;   // 8 x bf16 fragment
typedef __attribute__((ext_vector_type(4))) float f4v;   // 4 x f32 accum

__device__ inline unsigned short f2bf(float f) {
  union { float f; unsigned u; } v;
  v.f = f;
  unsigned r = (v.u + 0x7FFFu + ((v.u >> 16) & 1u)) >> 16;  // RNE
  return (unsigned short)r;
}

__device__ inline unsigned short f2bf_trunc(float f) {
  union { float f; unsigned u; } v;
  v.f = f;
  return (unsigned short)(v.u >> 16);
}

// packed f32x2 -> bf16x2 (RNE), src0 -> low16, src1 -> high16
__device__ inline unsigned cvtpk(float lo, float hi) {
  unsigned r;
  asm("v_cvt_pk_bf16_f32 %0, %1, %2" : "=v"(r) : "v"(lo), "v"(hi));
  return r;
}

// async global->LDS, 16B per lane; l must be the wave-uniform base
__device__ inline void glds16(const unsigned short* g, unsigned short* l) {
  __builtin_amdgcn_global_load_lds(
      (const __attribute__((address_space(1))) unsigned*)g,
      (__attribute__((address_space(3))) unsigned*)l, 16, 0, 0);
}

// ---------------------------------------------------------------------------
// Kernel 0: W [1024][64] f32 x3 -> WTswz [192][1024] bf16, XOR-swizzled:
//   storage 16B-unit c8 of row r holds logical unit (c8&~7)|((c8&7)^(r&7)).
// ---------------------------------------------------------------------------
__global__ __launch_bounds__(256) void conv_wt_kernel(
    const float* __restrict__ Wq, const float* __restrict__ Wk,
    const float* __restrict__ Wv, unsigned short* __restrict__ WTswz) {
  const int idx = blockIdx.x * 256 + threadIdx.x;  // 192*128 = 24576
  const int r = idx >> 7;          // output row 0..191
  const int c8 = idx & 127;        // storage 16B-unit
  const int l8 = (c8 & ~7) | ((c8 & 7) ^ (r & 7));
  const int n0 = l8 * 8;
  const int m = r >> 6, h = r & 63;
  const float* W = (m == 0) ? Wq : (m == 1) ? Wk : Wv;
  unsigned short v[8];
#pragma unroll
  for (int j = 0; j < 8; ++j) v[j] = f2bf(W[(size_t)(n0 + j) * HH + h]);
  *reinterpret_cast<uint4*>(WTswz + (size_t)r * NE + c8 * 8) =
      *reinterpret_cast<const uint4*>(v);
}

// ---------------------------------------------------------------------------
// Kernel 1: QKV projection, m97-style pipelined MFMA GEMM (round-7 version).
//   NEW: Q epilogue pre-scales by 0.125*log2(e) so attention's scores come
//   out of QK^T already in log2 domain (saves 16 VALU/tile in attn).
// ---------------------------------------------------------------------------
__global__ __launch_bounds__(256, 2) void qkv_proj_mfma(
    const float* __restrict__ x, const unsigned short* __restrict__ WTswz,
    unsigned short* __restrict__ Q, unsigned short* __restrict__ K,
    unsigned short* __restrict__ VT) {
  __shared__ __align__(16) unsigned short Abuf[2][32 * 72];   //  4.5 KB each
  __shared__ __align__(16) unsigned short Bbuf[2][192 * 64];  // 24   KB each

  const int tid = threadIdx.x;
  const int lane = tid & 63;
  const int w = tid >> 6;
  const int rg = w & 1, cg = w >> 1;
  const int lr = lane & 15, lg = lane >> 4;
  const int row0 = blockIdx.x * 32;

  const int arow = tid >> 3, aunit = tid & 7;
  const float* __restrict__ xrow = x + (size_t)(row0 + arow) * NE + aunit * 8;
  unsigned short* const awr = &Abuf[0][0] + arow * 72 + aunit * 8;  // +buf*2304

  const int bcol = w * 48 + (lane >> 3);          // + j*8
  const unsigned short* const bsrc0 =
      WTswz + (size_t)bcol * NE + (lane & 7) * 8;  // + j*8*NE + kc
  unsigned short* const bdst0 = &Bbuf[0][0] + (w * 48) * 64;  // + j*512 + buf*12288

  f4v acc[6];
#pragma unroll
  for (int c = 0; c < 6; ++c) acc[c] = (f4v)0.f;

  // ---- prologue: stage tile 0 into buf 0
  float4 a0 = *reinterpret_cast<const float4*>(xrow);
  float4 a1 = *reinterpret_cast<const float4*>(xrow + 4);
#pragma unroll
  for (int j = 0; j < 6; ++j)
    glds16(bsrc0 + (size_t)j * 8 * NE, bdst0 + j * 512);
  {
    unsigned au[4] = {cvtpk(a0.x, a0.y), cvtpk(a0.z, a0.w),
                      cvtpk(a1.x, a1.y), cvtpk(a1.z, a1.w)};
    *reinterpret_cast<uint4*>(awr) = *reinterpret_cast<const uint4*>(au);
  }
  __syncthreads();

  int cur = 0;
  for (int t = 0; t < 16; ++t) {
    const int kcn = (t + 1) * 64;
    if (t < 15) {  // issue next tile's loads before compute (T14/T3)
      a0 = *reinterpret_cast<const float4*>(xrow + kcn);
      a1 = *reinterpret_cast<const float4*>(xrow + kcn + 4);
#pragma unroll
      for (int j = 0; j < 6; ++j)
        glds16(bsrc0 + (size_t)j * 8 * NE + kcn,
               bdst0 + (cur ^ 1) * 12288 + j * 512);
    }
    // ---- compute from buf[cur]
    const unsigned short* Ab = &Abuf[cur][0];
    const unsigned short* Bb = &Bbuf[cur][0];
#pragma unroll
    for (int ks = 0; ks < 2; ++ks) {  // k-slices of 32
      const s8v a = *reinterpret_cast<const s8v*>(
          Ab + (rg * 16 + lr) * 72 + ks * 32 + lg * 8);
#pragma unroll
      for (int c = 0; c < 6; ++c) {
        const int col = cg * 96 + c * 16 + lr;
        const int uraw = (lg + ks * 4) ^ (lr & 7);
        const s8v b = *reinterpret_cast<const s8v*>(Bb + col * 64 + uraw * 8);
        acc[c] = __builtin_amdgcn_mfma_f32_16x16x32_bf16(a, b, acc[c], 0, 0, 0);
      }
    }
    if (t < 15) {
      unsigned au[4] = {cvtpk(a0.x, a0.y), cvtpk(a0.z, a0.w),
                        cvtpk(a1.x, a1.y), cvtpk(a1.z, a1.w)};
      *reinterpret_cast<uint4*>(awr + (cur ^ 1) * 2304) =
          *reinterpret_cast<const uint4*>(au);
      __syncthreads();  // drains glds (vmcnt) + ds_write, then barrier
      cur ^= 1;
    }
  }

  // ---- epilogue (Q pre-scaled into log2-softmax domain)
  const float QSCL = 0.18033688011112042f;  // 0.125 * log2(e)
#pragma unroll
  for (int c = 0; c < 6; ++c) {
    const int col = cg * 96 + c * 16 + lr;
    const int m = col >> 6;  // uniform per (cg,c)
    const int h = col & 63;
#pragma unroll
    for (int r = 0; r < 4; ++r) {
      const int rr = row0 + rg * 16 + lg * 4 + r;  // D: row=(lane>>4)*4+reg
      if (m == 0) {
        Q[(size_t)rr * HH + h] = f2bf(acc[c][r] * QSCL);
      } else if (m == 1) {
        K[(size_t)rr * HH + h] = f2bf(acc[c][r]);
      } else {
        const int bb = rr >> 11, tt2 = rr & (TT - 1);
        VT[((size_t)bb * HH + h) * TT + tt2] = f2bf(acc[c][r]);
      }
    }
  }
}

// ---------------------------------------------------------------------------
// Kernel 2: causal flash attention, in-block split-k.  1024 blocks x 4 waves.
//   Round-7 changes: LPT dispatch (qt descending -> longest blocks first),
//   Q pre-scaled (no per-score mul), T13 defer-max (skip rescale unless
//   growth > 8, wave-uniform), T5 setprio around MFMA clusters.
// ---------------------------------------------------------------------------
__global__ __launch_bounds__(256, 4) void flash_attn_mfma(
    const unsigned short* __restrict__ Q, const unsigned short* __restrict__ K,
    const unsigned short* __restrict__ VT, float* __restrict__ out) {
  __shared__ unsigned short pl[4][16][72];
  __shared__ float ol[4][16][64];
  __shared__ float ml[4][16];
  __shared__ float ll[4][16];

  const int tid = threadIdx.x;
  const int lane = tid & 63;
  const int w = tid >> 6;
  const int lr = lane & 15;
  const int lg = lane >> 4;
  const int bid = blockIdx.x;
  const int b = bid & 7;
  const int qt = 127 - (bid >> 3);  // LPT: longest q-tiles dispatched first
  const int q0 = qt * 16;
  const size_t rowbase = (size_t)b * TT;

  const int nt = (qt >> 2) + 1;     // k-tiles of 64 covering rows < q0+16
  const int base = nt >> 2, rem = nt & 3;
  const int t0 = w * base + (w < rem ? w : rem);
  const int cnt = base + (w < rem ? 1 : 0);

  const s8v qf0 = *reinterpret_cast<const s8v*>(
      Q + (rowbase + q0 + lr) * HH + lg * 8);
  const s8v qf1 = *reinterpret_cast<const s8v*>(
      Q + (rowbase + q0 + lr) * HH + 32 + lg * 8);

  f4v o[4];
#pragma unroll
  for (int n = 0; n < 4; ++n) o[n] = (f4v)0.f;
  float mrow[4], lrow[4];
#pragma unroll
  for (int r = 0; r < 4; ++r) { mrow[r] = -INFINITY; lrow[r] = 0.f; }

  for (int kt = t0; kt < t0 + cnt; ++kt) {
    const int k0 = kt * 64;
    f4v s[4];
#pragma unroll
    for (int nk = 0; nk < 4; ++nk) s[nk] = (f4v)0.f;
    __builtin_amdgcn_s_setprio(1);
#pragma unroll
    for (int nk = 0; nk < 4; ++nk) {
      const unsigned short* kp = K + (rowbase + k0 + 16 * nk + lr) * HH + lg * 8;
      const s8v kf0 = *reinterpret_cast<const s8v*>(kp);
      const s8v kf1 = *reinterpret_cast<const s8v*>(kp + 32);
      s[nk] = __builtin_amdgcn_mfma_f32_16x16x32_bf16(qf0, kf0, s[nk], 0, 0, 0);
      s[nk] = __builtin_amdgcn_mfma_f32_16x16x32_bf16(qf1, kf1, s[nk], 0, 0, 0);
    }
    __builtin_amdgcn_s_setprio(0);
    // hoist V loads: L2 latency hides under softmax
    s8v vfr[2][4];
#pragma unroll
    for (int kh = 0; kh < 2; ++kh)
#pragma unroll
      for (int n = 0; n < 4; ++n)
        vfr[kh][n] = *reinterpret_cast<const s8v*>(
            VT + ((size_t)b * HH + 16 * n + lr) * TT + k0 + kh * 32 + lg * 8);

    // scores are already log2-domain (Q pre-scaled); only mask on diag tile
    if (kt == nt - 1) {
#pragma unroll
      for (int nk = 0; nk < 4; ++nk) {
        const int kk = k0 + 16 * nk + lr;
#pragma unroll
        for (int r = 0; r < 4; ++r) {
          const int qq = q0 + lg * 4 + r;
          if (kk > qq) s[nk][r] = -INFINITY;
        }
      }
    }

    // row max (16-lane reduce) + T13 defer-max decision
    float mx_[4];
    float grow = -INFINITY;
#pragma unroll
    for (int r = 0; r < 4; ++r) {
      float mx = fmaxf(fmaxf(s[0][r], s[1][r]), fmaxf(s[2][r], s[3][r]));
#pragma unroll
      for (int off = 1; off < 16; off <<= 1)
        mx = fmaxf(mx, __shfl_xor(mx, off));
      mx_[r] = mx;
      grow = fmaxf(grow, mx - mrow[r]);
    }
    if (!__all(grow <= 8.f)) {  // wave-uniform rescale (rare after warmup)
#pragma unroll
      for (int r = 0; r < 4; ++r) {
        const float mnew = fmaxf(mrow[r], mx_[r]);
        const float scl = exp2f(mrow[r] - mnew);
        mrow[r] = mnew;
        lrow[r] *= scl;
#pragma unroll
        for (int n = 0; n < 4; ++n) o[n][r] *= scl;
      }
    }
    // p = exp2(s - m) (m possibly deferred; p bounded by 2^8), row-sum
#pragma unroll
    for (int r = 0; r < 4; ++r) {
      float rs = 0.f;
#pragma unroll
      for (int nk = 0; nk < 4; ++nk) {
        const float p = exp2f(s[nk][r] - mrow[r]);
        s[nk][r] = p;
        rs += p;
      }
#pragma unroll
      for (int off = 1; off < 16; off <<= 1)
        rs += __shfl_xor(rs, off);
      lrow[r] += rs;
    }
    // P: D-layout -> per-wave LDS (no barrier needed)
#pragma unroll
    for (int nk = 0; nk < 4; ++nk)
#pragma unroll
      for (int r = 0; r < 4; ++r)
        pl[w][lg * 4 + r][16 * nk + lr] = f2bf_trunc(s[nk][r]);
    // PV
#pragma unroll
    for (int kh = 0; kh < 2; ++kh) {
      const int pc = kh * 32 + lg * 8;
      const ushort4 plo = *reinterpret_cast<const ushort4*>(&pl[w][lr][pc]);
      const ushort4 phi = *reinterpret_cast<const ushort4*>(&pl[w][lr][pc + 4]);
      s8v pa;
      pa[0] = plo.x; pa[1] = plo.y; pa[2] = plo.z; pa[3] = plo.w;
      pa[4] = phi.x; pa[5] = phi.y; pa[6] = phi.z; pa[7] = phi.w;
      __builtin_amdgcn_s_setprio(1);
#pragma unroll
      for (int n = 0; n < 4; ++n)
        o[n] = __builtin_amdgcn_mfma_f32_16x16x32_bf16(pa, vfr[kh][n], o[n], 0, 0, 0);
      __builtin_amdgcn_s_setprio(0);
    }
  }

  // publish per-wave partials
#pragma unroll
  for (int n = 0; n < 4; ++n)
#pragma unroll
    for (int r = 0; r < 4; ++r) ol[w][lg * 4 + r][16 * n + lr] = o[n][r];
  if (lr == 0) {
#pragma unroll
    for (int r = 0; r < 4; ++r) {
      ml[w][lg * 4 + r] = mrow[r];
      ll[w][lg * 4 + r] = lrow[r];
    }
  }
  __syncthreads();

  // combine: thread -> (row = tid>>4, 4 cols at (tid&15)*4)
  const int row = tid >> 4;
  const int c0 = (tid & 15) * 4;
  float m0 = ml[0][row], m1 = ml[1][row], m2 = ml[2][row], m3 = ml[3][row];
  const float ms = fmaxf(fmaxf(m0, m1), fmaxf(m2, m3));
  const float w0 = exp2f(m0 - ms), w1 = exp2f(m1 - ms);
  const float w2 = exp2f(m2 - ms), w3 = exp2f(m3 - ms);
  const float lsum = w0 * ll[0][row] + w1 * ll[1][row] +
                     w2 * ll[2][row] + w3 * ll[3][row];
  float4 osum;
  osum.x = w0 * ol[0][row][c0 + 0] + w1 * ol[1][row][c0 + 0] +
           w2 * ol[2][row][c0 + 0] + w3 * ol[3][row][c0 + 0];
  osum.y = w0 * ol[0][row][c0 + 1] + w1 * ol[1][row][c0 + 1] +
           w2 * ol[2][row][c0 + 1] + w3 * ol[3][row][c0 + 1];
  osum.z = w0 * ol[0][row][c0 + 2] + w1 * ol[1][row][c0 + 2] +
           w2 * ol[2][row][c0 + 2] + w3 * ol[3][row][c0 + 2];
  osum.w = w0 * ol[0][row][c0 + 3] + w1 * ol[1][row][c0 + 3] +
           w2 * ol[2][row][c0 + 3] + w3 * ol[3][row][c0 + 3];
  const float inv = 1.0f / lsum;
  float4 res;
  res.x = osum.x * inv; res.y = osum.y * inv;
  res.z = osum.z * inv; res.w = osum.w * inv;
  *reinterpret_cast<float4*>(out + (rowbase + q0 + row) * HH + c0) = res;
}

extern "C" void kernel_launch(void* const* d_in, const int* in_sizes, int n_in,
                              void* d_out, int out_size, void* d_ws, size_t ws_size,
                              hipStream_t stream) {
  const float* x  = (const float*)d_in[0];
  const float* Wk = (const float*)d_in[1];
  const float* Wq = (const float*)d_in[2];
  const float* Wv = (const float*)d_in[3];
  float* out = (float*)d_out;

  unsigned short* ws = (unsigned short*)d_ws;
  unsigned short* Q  = ws;                           // BT*HH bf16
  unsigned short* K  = ws + (size_t)BT * HH;         // BT*HH bf16
  unsigned short* VT = ws + 2 * (size_t)BT * HH;     // B*HH*TT bf16
  unsigned short* WT = ws + 3 * (size_t)BT * HH;     // 192*1024 bf16 (swizzled)

  conv_wt_kernel<<<96, 256, 0, stream>>>(Wq, Wk, Wv, WT);
  qkv_proj_mfma<<<512, 256, 0, stream>>>(x, WT, Q, K, VT);
  flash_attn_mfma<<<1024, 256, 0, stream>>>(Q, K, VT, out);
}